// Round 3
// baseline (356.364 us; speedup 1.0000x reference)
//
#include <hip/hip_runtime.h>
#include <stdint.h>

typedef unsigned short u16;
typedef __attribute__((ext_vector_type(8))) short short8;    // 8 bf16 (4 VGPRs)
typedef __attribute__((ext_vector_type(16))) float f32x16;

#define ATTN_SCALE 0.08838834764831845f   // 1/sqrt(128)

__device__ __forceinline__ u16 f2bf(float f) {
  union { float f; uint32_t u; } a; a.f = f;
  return (u16)((a.u + 0x7fffu + ((a.u >> 16) & 1u)) >> 16);   // RNE
}

__device__ __forceinline__ void async16(const u16* g, u16* lds) {
  __builtin_amdgcn_global_load_lds(
      (const __attribute__((address_space(1))) void*)g,
      (__attribute__((address_space(3))) void*)lds, 16, 0, 0);
}

// ---------------- fp32 -> bf16 conversion (8 elems/thread) ----------------
__global__ void cvt_kernel(const float* __restrict__ src, u16* __restrict__ dst, int n8) {
  int i = blockIdx.x * 256 + threadIdx.x;
  if (i >= n8) return;
  const float4* s4 = (const float4*)src;
  float4 a = s4[2 * i], c = s4[2 * i + 1];
  union { u16 h[8]; uint4 v; } o;
  o.h[0] = f2bf(a.x); o.h[1] = f2bf(a.y); o.h[2] = f2bf(a.z); o.h[3] = f2bf(a.w);
  o.h[4] = f2bf(c.x); o.h[5] = f2bf(c.y); o.h[6] = f2bf(c.z); o.h[7] = f2bf(c.w);
  ((uint4*)dst)[i] = o.v;
}

__global__ void cvtw_kernel(const float* __restrict__ w0, const float* __restrict__ w1,
                            const float* __restrict__ w2, u16* __restrict__ dst) {
  int z = blockIdx.y;
  const float* src = (z == 0) ? w0 : (z == 1) ? w1 : w2;
  int i = blockIdx.x * 256 + threadIdx.x;
  const float4* s4 = (const float4*)src;
  float4 a = s4[2 * i], c = s4[2 * i + 1];
  union { u16 h[8]; uint4 v; } o;
  o.h[0] = f2bf(a.x); o.h[1] = f2bf(a.y); o.h[2] = f2bf(a.z); o.h[3] = f2bf(a.w);
  o.h[4] = f2bf(c.x); o.h[5] = f2bf(c.y); o.h[6] = f2bf(c.z); o.h[7] = f2bf(c.w);
  ((uint4*)(dst + (size_t)z * 4194304))[i] = o.v;
}

// ---------------- QKV projection v5: 256x256, BK=64, m201 4-phase cadence ---
// 8 waves (512 thr), per-wave output 128x64 (acc[4][2] of 32x32).
// LDS: 4 chunk-slots of [256 rows x 32 cols] per matrix (A,B) = 128 KB.
// Tile kt occupies slots {(2kt)&3, (2kt+1)&3}; double-buffered at chunk level.
// Per K-tile: 4 phases (kk granule), each:
//   {6 ds_read frags | 2 global_load_lds staging | barrier | lgkmcnt(0) |
//    setprio(1) | 8 MFMA | setprio(0) | [vmcnt(4) @ph1/ph3] | barrier}
// Staging: ph0=A-chunk0', ph1=B-chunk0', ph2=A-chunk1', ph3=B-chunk1'.
// vmcnt ledger (steady): outstanding oscillates 4<->8; vmcnt(4) at end-ph1
// retires chunk1-kt (read at ph2); at end-ph3 retires chunk0-(kt+1) (read at
// next ph0). Never vmcnt(0) except the kt=31 tail.
// Chunk LDS layout (proven 0-conflict): granule s: R=s>>4, j=s&15, u=j^(R&15),
// m=4R+(u>>2), c=u&3; data = M[m][c*8..+8] of the 256x32 chunk.
__global__ __launch_bounds__(512, 2) void qkv_gemm(
    const u16* __restrict__ xb, const u16* __restrict__ Wb,
    const float* __restrict__ bq, const float* __restrict__ bk, const float* __restrict__ bv,
    u16* __restrict__ qkv) {
  extern __shared__ __align__(16) u16 smem[];   // 128 KB
  u16* As = smem;            // [4][8192]
  u16* Bs = smem + 32768;    // [4][8192]
  const int z = blockIdx.z;
  const int n0 = blockIdx.x * 256, m0 = blockIdx.y * 256;
  const u16* Bw = Wb + (size_t)z * 4194304u;
  const float* bias = (z == 0) ? bq : (z == 1) ? bk : bv;
  u16* dst = qkv + (size_t)z * 8388608u;
  const int t = threadIdx.x;                 // 0..511
  const int wave = t >> 6, lane = t & 63;
  const int wm = wave >> 2, wn = wave & 3, l31 = lane & 31, h = lane >> 5;

  // staging: 1024 granules (16 KB) per matrix per chunk; s = p*512 + t
  int soff[2], goff[2];
#pragma unroll
  for (int p = 0; p < 2; ++p) {
    const int s = p * 512 + t;
    const int R = s >> 4, j = s & 15, u = j ^ (R & 15);
    const int m = 4 * R + (u >> 2), c = u & 3;
    soff[p] = s * 8;                       // LDS elem offset within chunk
    goff[p] = m * 2048 + c * 8;            // global elem offset within tile rows
  }
  // frag-read precompute
  const int q4 = (l31 & 3) * 4;
  int fr16A[4], fR15A[4], fr16B[2], fR15B[2];
#pragma unroll
  for (int am = 0; am < 4; ++am) {
    const int mA = wm * 128 + am * 32 + l31;
    fr16A[am] = (mA >> 2) * 16; fR15A[am] = (mA >> 2) & 15;
  }
#pragma unroll
  for (int bn = 0; bn < 2; ++bn) {
    const int mB = wn * 64 + bn * 32 + l31;
    fr16B[bn] = (mB >> 2) * 16; fR15B[bn] = (mB >> 2) & 15;
  }

  f32x16 acc[4][2];
#pragma unroll
  for (int am = 0; am < 4; ++am)
#pragma unroll
    for (int bn = 0; bn < 2; ++bn)
#pragma unroll
      for (int r = 0; r < 16; ++r) acc[am][bn][r] = 0.f;

  const u16* Abase = xb + (size_t)m0 * 2048;
  const u16* Bbase = Bw + (size_t)n0 * 2048;

  // prologue: stage both chunks of tile 0 into slots 0,1 (order Ac0,Bc0,Ac1,Bc1)
#pragma unroll
  for (int ch = 0; ch < 2; ++ch) {
    const int k0 = ch * 32;
#pragma unroll
    for (int p = 0; p < 2; ++p) async16(Abase + goff[p] + k0, &As[ch * 8192 + soff[p]]);
#pragma unroll
    for (int p = 0; p < 2; ++p) async16(Bbase + goff[p] + k0, &Bs[ch * 8192 + soff[p]]);
  }
  asm volatile("s_waitcnt vmcnt(4)" ::: "memory");   // chunk0 of tile 0 landed
  __builtin_amdgcn_s_barrier();

#pragma unroll 1
  for (int kt = 0; kt < 32; ++kt) {
    const int stage = (kt + 1 < 32);
#pragma unroll
    for (int ph = 0; ph < 4; ++ph) {
      const int slot = ((2 * kt + (ph >> 1)) & 3) * 8192;
      const int c = (ph & 1) * 2 + h;
      short8 af[4], bf[2];
#pragma unroll
      for (int am = 0; am < 4; ++am)
        af[am] = *(const short8*)&As[slot + (fr16A[am] + ((q4 + c) ^ fR15A[am])) * 8];
#pragma unroll
      for (int bn = 0; bn < 2; ++bn)
        bf[bn] = *(const short8*)&Bs[slot + (fr16B[bn] + ((q4 + c) ^ fR15B[bn])) * 8];

      if (stage) {                          // 2 loads/phase: A or B half-chunk
        const int ch = ph >> 1;
        const int k0 = (kt + 1) * 64 + ch * 32;
        const int ws = ((2 * kt + 2 + ch) & 3) * 8192;
        if ((ph & 1) == 0) {
#pragma unroll
          for (int p = 0; p < 2; ++p) async16(Abase + goff[p] + k0, &As[ws + soff[p]]);
        } else {
#pragma unroll
          for (int p = 0; p < 2; ++p) async16(Bbase + goff[p] + k0, &Bs[ws + soff[p]]);
        }
      }

      __builtin_amdgcn_s_barrier();
      asm volatile("s_waitcnt lgkmcnt(0)" ::: "memory");
      __builtin_amdgcn_s_setprio(1);
#pragma unroll
      for (int am = 0; am < 4; ++am)
#pragma unroll
        for (int bn = 0; bn < 2; ++bn)
          acc[am][bn] = __builtin_amdgcn_mfma_f32_32x32x16_bf16(af[am], bf[bn], acc[am][bn], 0, 0, 0);
      __builtin_amdgcn_s_setprio(0);

      if (ph == 1) {
        if (stage) asm volatile("s_waitcnt vmcnt(4)" ::: "memory");  // chunk1-kt in
        else       asm volatile("s_waitcnt vmcnt(0)" ::: "memory");  // kt=31 tail
      } else if (ph == 3) {
        if (stage) asm volatile("s_waitcnt vmcnt(4)" ::: "memory");  // chunk0-kt+1 in
      }
      __builtin_amdgcn_s_barrier();
    }
  }

  // C layout (32x32): col(n)=l31, row(m) = 8g + 4h + rr, reg = 4g + rr
#pragma unroll
  for (int bn = 0; bn < 2; ++bn) {
    const int col = n0 + wn * 64 + bn * 32 + l31;
    const float bb_ = bias[col];
    const int hh = col >> 7, hd = col & 127;
#pragma unroll
    for (int am = 0; am < 4; ++am) {
#pragma unroll
      for (int g = 0; g < 4; ++g) {
        const int lbase = m0 + wm * 128 + am * 32 + 8 * g + 4 * h;
        const int bb = lbase >> 11, l0 = lbase & 2047;
        if (z == 2) {
          union { u16 q[4]; uint2 d; } pk;
#pragma unroll
          for (int rr = 0; rr < 4; ++rr) pk.q[rr] = f2bf(acc[am][bn][4 * g + rr] + bb_);
          *(uint2*)&dst[((size_t)(bb * 16 + hh) * 128 + hd) * 2048 + l0] = pk.d;
        } else {
#pragma unroll
          for (int rr = 0; rr < 4; ++rr)
            dst[((size_t)(bb * 16 + hh) * 2048 + (l0 + rr)) * 128 + hd] =
                f2bf(acc[am][bn][4 * g + rr] + bb_);
        }
      }
    }
  }
}

// ---------------- attention v5: Tk=64 double-buffered (unchanged this round)
__global__ __launch_bounds__(256, 2) void attn_kernel(
    const u16* __restrict__ Qg,   // [32][2048][128]
    const u16* __restrict__ Kg,   // [32][2048][128]
    const u16* __restrict__ Vtg,  // [32][128][2048]
    float* __restrict__ out) {    // [2][2048][2048] fp32
  __shared__ __align__(16) u16 Ks[2][64 * 128];   // swizzled g^(row&15)
  __shared__ __align__(16) u16 Vs[2][128 * 64];   // swizzled g^(row&7)
  const int bh = blockIdx.y, q0 = blockIdx.x * 128;
  const int t = threadIdx.x, wave = t >> 6, lane = t & 63;
  const int l31 = lane & 31, h = lane >> 5;
  const u16* Qp = Qg + (size_t)bh * 262144;
  const u16* Kp = Kg + (size_t)bh * 262144;
  const u16* Vp = Vtg + (size_t)bh * 262144;
  const int b = bh >> 4, hd = bh & 15;
  const int qrow = q0 + wave * 32 + l31;

  short8 qf[8];
#pragma unroll
  for (int s = 0; s < 8; ++s)
    qf[s] = *(const short8*)&Qp[(size_t)qrow * 128 + s * 16 + h * 8];

  int kOff[4], kSlot[4], vOff[4], vSlot[4];
#pragma unroll
  for (int p = 0; p < 4; ++p) {
    const int s = p * 256 + wave * 64 + lane;
    const int rk = s >> 4, gk = (s & 15) ^ (rk & 15);
    kSlot[p] = s * 8; kOff[p] = rk * 128 + gk * 8;
    const int rv = s >> 3, gv = (s & 7) ^ (rv & 7);
    vSlot[p] = s * 8; vOff[p] = rv * 2048 + gv * 8;
  }

  f32x16 oac[4];
#pragma unroll
  for (int dt = 0; dt < 4; ++dt)
#pragma unroll
    for (int r = 0; r < 16; ++r) oac[dt][r] = 0.f;
  float den = 0.f;

#pragma unroll
  for (int p = 0; p < 4; ++p) async16(Kp + kOff[p], &Ks[0][kSlot[p]]);
#pragma unroll
  for (int p = 0; p < 4; ++p) async16(Vp + vOff[p], &Vs[0][vSlot[p]]);

#pragma unroll 1
  for (int kt = 0; kt < 32; ++kt) {
    __syncthreads();                    // tile kt staged; prev-iter reads done
    const int cur = kt & 1;
    if (kt + 1 < 32) {                  // prefetch tile kt+1 (overlaps compute)
      const int k1 = (kt + 1) * 64;
#pragma unroll
      for (int p = 0; p < 4; ++p)
        async16(Kp + (size_t)k1 * 128 + kOff[p], &Ks[cur ^ 1][kSlot[p]]);
#pragma unroll
      for (int p = 0; p < 4; ++p)
        async16(Vp + (size_t)k1 + vOff[p], &Vs[cur ^ 1][vSlot[p]]);
    }

#pragma unroll
    for (int T = 0; T < 2; ++T) {
      const int krow = T * 32 + l31;
      f32x16 sc;
#pragma unroll
      for (int r = 0; r < 16; ++r) sc[r] = 0.f;
#pragma unroll
      for (int s = 0; s < 8; ++s) {
        const short8 kf = *(const short8*)&Ks[cur][(krow * 16 + ((2 * s + h) ^ (krow & 15))) * 8];
        sc = __builtin_amdgcn_mfma_f32_32x32x16_bf16(kf, qf[s], sc, 0, 0, 0);
      }
      uint32_t pp[8];
#pragma unroll
      for (int i = 0; i < 8; ++i) {
        const float e0 = __expf(fminf(sc[2 * i] * ATTN_SCALE, 80.f));
        const float e1 = __expf(fminf(sc[2 * i + 1] * ATTN_SCALE, 80.f));
        den += e0 + e1;
        union { float f; uint32_t u; } u0, u1; u0.f = e0; u1.f = e1;
        pp[i] = ((u1.u + 0x8000u) & 0xffff0000u) | ((u0.u + 0x8000u) >> 16);
      }
      uint32_t x[8];
#pragma unroll
      for (int i = 0; i < 8; ++i) x[i] = __shfl_xor(pp[i], 32, 64);
#pragma unroll
      for (int ks = 0; ks < 2; ++ks) {
        const int o0 = ks * 4;
        union { uint32_t u[4]; short8 s8; } bfp;
        bfp.u[0] = h ? x[o0 + 2] : pp[o0 + 0];
        bfp.u[1] = h ? x[o0 + 3] : pp[o0 + 1];
        bfp.u[2] = h ? pp[o0 + 2] : x[o0 + 0];
        bfp.u[3] = h ? pp[o0 + 3] : x[o0 + 1];
        const int gk = T * 4 + ks * 2 + h;   // k-granule 0..7 in V tile
#pragma unroll
        for (int dt = 0; dt < 4; ++dt) {
          const int vrow = dt * 32 + l31;
          const short8 vf = *(const short8*)&Vs[cur][(vrow * 8 + (gk ^ (vrow & 7))) * 8];
          oac[dt] = __builtin_amdgcn_mfma_f32_32x32x16_bf16(vf, bfp.s8, oac[dt], 0, 0, 0);
        }
      }
    }
  }

  den += __shfl_xor(den, 32, 64);
  const float inv = 1.f / den;
#pragma unroll
  for (int dt = 0; dt < 4; ++dt) {
#pragma unroll
    for (int g4 = 0; g4 < 4; ++g4) {
      float4 o;
      o.x = oac[dt][4 * g4 + 0] * inv;
      o.y = oac[dt][4 * g4 + 1] * inv;
      o.z = oac[dt][4 * g4 + 2] * inv;
      o.w = oac[dt][4 * g4 + 3] * inv;
      const int d = dt * 32 + g4 * 8 + h * 4;
      *(float4*)&out[((size_t)(b * 2048 + qrow)) * 2048 + hd * 128 + d] = o;
    }
  }
}

extern "C" void kernel_launch(void* const* d_in, const int* in_sizes, int n_in,
                              void* d_out, int out_size, void* d_ws, size_t ws_size,
                              hipStream_t stream) {
  const float* x  = (const float*)d_in[0];
  const float* Wq = (const float*)d_in[1];
  const float* bq = (const float*)d_in[2];
  const float* Wk = (const float*)d_in[3];
  const float* bk = (const float*)d_in[4];
  const float* Wv = (const float*)d_in[5];
  const float* bv = (const float*)d_in[6];
  float* out = (float*)d_out;
  if (ws_size < 92274688u) return;

  u16* xb  = (u16*)d_ws;             // [4096][2048] bf16
  u16* Wb  = xb + 8388608;           // [3][2048][2048] bf16
  u16* qkv = Wb + 12582912;          // Q | K | V^T bf16

  cvt_kernel<<<4096, 256, 0, stream>>>(x, xb, 1048576);
  cvtw_kernel<<<dim3(2048, 3), 256, 0, stream>>>(Wq, Wk, Wv, Wb);
  qkv_gemm<<<dim3(8, 16, 3), 512, 131072, stream>>>(xb, Wb, bq, bk, bv, qkv);
  attn_kernel<<<dim3(16, 32), 256, 0, stream>>>(qkv, qkv + 8388608, qkv + 16777216, out);
}

// Round 4
// 353.549 us; speedup vs baseline: 1.0080x; 1.0080x over previous
//
#include <hip/hip_runtime.h>
#include <stdint.h>

typedef unsigned short u16;
typedef __attribute__((ext_vector_type(8))) short short8;    // 8 bf16 (4 VGPRs)
typedef __attribute__((ext_vector_type(16))) float f32x16;

#define ATTN_SCALE 0.08838834764831845f   // 1/sqrt(128)

__device__ __forceinline__ u16 f2bf(float f) {
  union { float f; uint32_t u; } a; a.f = f;
  return (u16)((a.u + 0x7fffu + ((a.u >> 16) & 1u)) >> 16);   // RNE
}

__device__ __forceinline__ void async16(const u16* g, u16* lds) {
  __builtin_amdgcn_global_load_lds(
      (const __attribute__((address_space(1))) void*)g,
      (__attribute__((address_space(3))) void*)lds, 16, 0, 0);
}

// ---------------- fp32 -> bf16 conversion (8 elems/thread) ----------------
__global__ void cvt_kernel(const float* __restrict__ src, u16* __restrict__ dst, int n8) {
  int i = blockIdx.x * 256 + threadIdx.x;
  if (i >= n8) return;
  const float4* s4 = (const float4*)src;
  float4 a = s4[2 * i], c = s4[2 * i + 1];
  union { u16 h[8]; uint4 v; } o;
  o.h[0] = f2bf(a.x); o.h[1] = f2bf(a.y); o.h[2] = f2bf(a.z); o.h[3] = f2bf(a.w);
  o.h[4] = f2bf(c.x); o.h[5] = f2bf(c.y); o.h[6] = f2bf(c.z); o.h[7] = f2bf(c.w);
  ((uint4*)dst)[i] = o.v;
}

__global__ void cvtw_kernel(const float* __restrict__ w0, const float* __restrict__ w1,
                            const float* __restrict__ w2, u16* __restrict__ dst) {
  int z = blockIdx.y;
  const float* src = (z == 0) ? w0 : (z == 1) ? w1 : w2;
  int i = blockIdx.x * 256 + threadIdx.x;
  const float4* s4 = (const float4*)src;
  float4 a = s4[2 * i], c = s4[2 * i + 1];
  union { u16 h[8]; uint4 v; } o;
  o.h[0] = f2bf(a.x); o.h[1] = f2bf(a.y); o.h[2] = f2bf(a.z); o.h[3] = f2bf(a.w);
  o.h[4] = f2bf(c.x); o.h[5] = f2bf(c.y); o.h[6] = f2bf(c.z); o.h[7] = f2bf(c.w);
  ((uint4*)(dst + (size_t)z * 4194304))[i] = o.v;
}

// ---------------- QKV projection v5: 256x256, BK=64, 4-phase cadence -------
// (unchanged this round -- attn is the target)
__global__ __launch_bounds__(512, 2) void qkv_gemm(
    const u16* __restrict__ xb, const u16* __restrict__ Wb,
    const float* __restrict__ bq, const float* __restrict__ bk, const float* __restrict__ bv,
    u16* __restrict__ qkv) {
  extern __shared__ __align__(16) u16 smem[];   // 128 KB
  u16* As = smem;            // [4][8192]
  u16* Bs = smem + 32768;    // [4][8192]
  const int z = blockIdx.z;
  const int n0 = blockIdx.x * 256, m0 = blockIdx.y * 256;
  const u16* Bw = Wb + (size_t)z * 4194304u;
  const float* bias = (z == 0) ? bq : (z == 1) ? bk : bv;
  u16* dst = qkv + (size_t)z * 8388608u;
  const int t = threadIdx.x;                 // 0..511
  const int wave = t >> 6, lane = t & 63;
  const int wm = wave >> 2, wn = wave & 3, l31 = lane & 31, h = lane >> 5;

  int soff[2], goff[2];
#pragma unroll
  for (int p = 0; p < 2; ++p) {
    const int s = p * 512 + t;
    const int R = s >> 4, j = s & 15, u = j ^ (R & 15);
    const int m = 4 * R + (u >> 2), c = u & 3;
    soff[p] = s * 8;
    goff[p] = m * 2048 + c * 8;
  }
  const int q4 = (l31 & 3) * 4;
  int fr16A[4], fR15A[4], fr16B[2], fR15B[2];
#pragma unroll
  for (int am = 0; am < 4; ++am) {
    const int mA = wm * 128 + am * 32 + l31;
    fr16A[am] = (mA >> 2) * 16; fR15A[am] = (mA >> 2) & 15;
  }
#pragma unroll
  for (int bn = 0; bn < 2; ++bn) {
    const int mB = wn * 64 + bn * 32 + l31;
    fr16B[bn] = (mB >> 2) * 16; fR15B[bn] = (mB >> 2) & 15;
  }

  f32x16 acc[4][2];
#pragma unroll
  for (int am = 0; am < 4; ++am)
#pragma unroll
    for (int bn = 0; bn < 2; ++bn)
#pragma unroll
      for (int r = 0; r < 16; ++r) acc[am][bn][r] = 0.f;

  const u16* Abase = xb + (size_t)m0 * 2048;
  const u16* Bbase = Bw + (size_t)n0 * 2048;

#pragma unroll
  for (int ch = 0; ch < 2; ++ch) {
    const int k0 = ch * 32;
#pragma unroll
    for (int p = 0; p < 2; ++p) async16(Abase + goff[p] + k0, &As[ch * 8192 + soff[p]]);
#pragma unroll
    for (int p = 0; p < 2; ++p) async16(Bbase + goff[p] + k0, &Bs[ch * 8192 + soff[p]]);
  }
  asm volatile("s_waitcnt vmcnt(4)" ::: "memory");
  __builtin_amdgcn_s_barrier();

#pragma unroll 1
  for (int kt = 0; kt < 32; ++kt) {
    const int stage = (kt + 1 < 32);
#pragma unroll
    for (int ph = 0; ph < 4; ++ph) {
      const int slot = ((2 * kt + (ph >> 1)) & 3) * 8192;
      const int c = (ph & 1) * 2 + h;
      short8 af[4], bf[2];
#pragma unroll
      for (int am = 0; am < 4; ++am)
        af[am] = *(const short8*)&As[slot + (fr16A[am] + ((q4 + c) ^ fR15A[am])) * 8];
#pragma unroll
      for (int bn = 0; bn < 2; ++bn)
        bf[bn] = *(const short8*)&Bs[slot + (fr16B[bn] + ((q4 + c) ^ fR15B[bn])) * 8];

      if (stage) {
        const int ch = ph >> 1;
        const int k0 = (kt + 1) * 64 + ch * 32;
        const int ws = ((2 * kt + 2 + ch) & 3) * 8192;
        if ((ph & 1) == 0) {
#pragma unroll
          for (int p = 0; p < 2; ++p) async16(Abase + goff[p] + k0, &As[ws + soff[p]]);
        } else {
#pragma unroll
          for (int p = 0; p < 2; ++p) async16(Bbase + goff[p] + k0, &Bs[ws + soff[p]]);
        }
      }

      __builtin_amdgcn_s_barrier();
      asm volatile("s_waitcnt lgkmcnt(0)" ::: "memory");
      __builtin_amdgcn_s_setprio(1);
#pragma unroll
      for (int am = 0; am < 4; ++am)
#pragma unroll
        for (int bn = 0; bn < 2; ++bn)
          acc[am][bn] = __builtin_amdgcn_mfma_f32_32x32x16_bf16(af[am], bf[bn], acc[am][bn], 0, 0, 0);
      __builtin_amdgcn_s_setprio(0);

      if (ph == 1) {
        if (stage) asm volatile("s_waitcnt vmcnt(4)" ::: "memory");
        else       asm volatile("s_waitcnt vmcnt(0)" ::: "memory");
      } else if (ph == 3) {
        if (stage) asm volatile("s_waitcnt vmcnt(4)" ::: "memory");
      }
      __builtin_amdgcn_s_barrier();
    }
  }

#pragma unroll
  for (int bn = 0; bn < 2; ++bn) {
    const int col = n0 + wn * 64 + bn * 32 + l31;
    const float bb_ = bias[col];
    const int hh = col >> 7, hd = col & 127;
#pragma unroll
    for (int am = 0; am < 4; ++am) {
#pragma unroll
      for (int g = 0; g < 4; ++g) {
        const int lbase = m0 + wm * 128 + am * 32 + 8 * g + 4 * h;
        const int bb = lbase >> 11, l0 = lbase & 2047;
        if (z == 2) {
          union { u16 q[4]; uint2 d; } pk;
#pragma unroll
          for (int rr = 0; rr < 4; ++rr) pk.q[rr] = f2bf(acc[am][bn][4 * g + rr] + bb_);
          *(uint2*)&dst[((size_t)(bb * 16 + hh) * 128 + hd) * 2048 + l0] = pk.d;
        } else {
#pragma unroll
          for (int rr = 0; rr < 4; ++rr)
            dst[((size_t)(bb * 16 + hh) * 2048 + (l0 + rr)) * 128 + hd] =
                f2bf(acc[am][bn][4 * g + rr] + bb_);
        }
      }
    }
  }
}

// ---------------- attention v6: XCD co-location swizzle -------------------
// K/V per head = 1 MB, re-read by 16 q-blocks. Default qb-fastest linear order
// round-robins those 16 blocks over all 8 XCDs -> per-XCD L2 working set =
// 32 heads x 1 MB = 32 MB >> 4 MB L2 -> all ~560 MB of K/V traffic goes L3.
// Remap so launch slot s runs work w=(s&7)*64+(s>>3): each XCD gets a
// contiguous 64-work chunk = 4 heads x 16 q-blocks -> K/V working set 4 MB,
// L2-resident. Bijective (512 % 8 == 0). Compute body unchanged from v5.
__global__ __launch_bounds__(256, 2) void attn_kernel(
    const u16* __restrict__ Qg,   // [32][2048][128]
    const u16* __restrict__ Kg,   // [32][2048][128]
    const u16* __restrict__ Vtg,  // [32][128][2048]
    float* __restrict__ out) {    // [2][2048][2048] fp32
  __shared__ __align__(16) u16 Ks[2][64 * 128];   // swizzled g^(row&15)
  __shared__ __align__(16) u16 Vs[2][128 * 64];   // swizzled g^(row&7)
  const int s_lin = blockIdx.y * 16 + blockIdx.x;        // launch slot 0..511
  const int w = (s_lin & 7) * 64 + (s_lin >> 3);         // work id (XCD chunks)
  const int bh = w >> 4, q0 = (w & 15) * 128;
  const int t = threadIdx.x, wave = t >> 6, lane = t & 63;
  const int l31 = lane & 31, h = lane >> 5;
  const u16* Qp = Qg + (size_t)bh * 262144;
  const u16* Kp = Kg + (size_t)bh * 262144;
  const u16* Vp = Vtg + (size_t)bh * 262144;
  const int b = bh >> 4, hd = bh & 15;
  const int qrow = q0 + wave * 32 + l31;

  short8 qf[8];
#pragma unroll
  for (int s = 0; s < 8; ++s)
    qf[s] = *(const short8*)&Qp[(size_t)qrow * 128 + s * 16 + h * 8];

  int kOff[4], kSlot[4], vOff[4], vSlot[4];
#pragma unroll
  for (int p = 0; p < 4; ++p) {
    const int s = p * 256 + wave * 64 + lane;
    const int rk = s >> 4, gk = (s & 15) ^ (rk & 15);
    kSlot[p] = s * 8; kOff[p] = rk * 128 + gk * 8;
    const int rv = s >> 3, gv = (s & 7) ^ (rv & 7);
    vSlot[p] = s * 8; vOff[p] = rv * 2048 + gv * 8;
  }

  f32x16 oac[4];
#pragma unroll
  for (int dt = 0; dt < 4; ++dt)
#pragma unroll
    for (int r = 0; r < 16; ++r) oac[dt][r] = 0.f;
  float den = 0.f;

#pragma unroll
  for (int p = 0; p < 4; ++p) async16(Kp + kOff[p], &Ks[0][kSlot[p]]);
#pragma unroll
  for (int p = 0; p < 4; ++p) async16(Vp + vOff[p], &Vs[0][vSlot[p]]);

#pragma unroll 1
  for (int kt = 0; kt < 32; ++kt) {
    __syncthreads();                    // tile kt staged; prev-iter reads done
    const int cur = kt & 1;
    if (kt + 1 < 32) {                  // prefetch tile kt+1 (overlaps compute)
      const int k1 = (kt + 1) * 64;
#pragma unroll
      for (int p = 0; p < 4; ++p)
        async16(Kp + (size_t)k1 * 128 + kOff[p], &Ks[cur ^ 1][kSlot[p]]);
#pragma unroll
      for (int p = 0; p < 4; ++p)
        async16(Vp + (size_t)k1 + vOff[p], &Vs[cur ^ 1][vSlot[p]]);
    }

#pragma unroll
    for (int T = 0; T < 2; ++T) {
      const int krow = T * 32 + l31;
      f32x16 sc;
#pragma unroll
      for (int r = 0; r < 16; ++r) sc[r] = 0.f;
#pragma unroll
      for (int s = 0; s < 8; ++s) {
        const short8 kf = *(const short8*)&Ks[cur][(krow * 16 + ((2 * s + h) ^ (krow & 15))) * 8];
        sc = __builtin_amdgcn_mfma_f32_32x32x16_bf16(kf, qf[s], sc, 0, 0, 0);
      }
      uint32_t pp[8];
#pragma unroll
      for (int i = 0; i < 8; ++i) {
        const float e0 = __expf(fminf(sc[2 * i] * ATTN_SCALE, 80.f));
        const float e1 = __expf(fminf(sc[2 * i + 1] * ATTN_SCALE, 80.f));
        den += e0 + e1;
        union { float f; uint32_t u; } u0, u1; u0.f = e0; u1.f = e1;
        pp[i] = ((u1.u + 0x8000u) & 0xffff0000u) | ((u0.u + 0x8000u) >> 16);
      }
      uint32_t x[8];
#pragma unroll
      for (int i = 0; i < 8; ++i) x[i] = __shfl_xor(pp[i], 32, 64);
#pragma unroll
      for (int ks = 0; ks < 2; ++ks) {
        const int o0 = ks * 4;
        union { uint32_t u[4]; short8 s8; } bfp;
        bfp.u[0] = h ? x[o0 + 2] : pp[o0 + 0];
        bfp.u[1] = h ? x[o0 + 3] : pp[o0 + 1];
        bfp.u[2] = h ? pp[o0 + 2] : x[o0 + 0];
        bfp.u[3] = h ? pp[o0 + 3] : x[o0 + 1];
        const int gk = T * 4 + ks * 2 + h;   // k-granule 0..7 in V tile
#pragma unroll
        for (int dt = 0; dt < 4; ++dt) {
          const int vrow = dt * 32 + l31;
          const short8 vf = *(const short8*)&Vs[cur][(vrow * 8 + (gk ^ (vrow & 7))) * 8];
          oac[dt] = __builtin_amdgcn_mfma_f32_32x32x16_bf16(vf, bfp.s8, oac[dt], 0, 0, 0);
        }
      }
    }
  }

  den += __shfl_xor(den, 32, 64);
  const float inv = 1.f / den;
#pragma unroll
  for (int dt = 0; dt < 4; ++dt) {
#pragma unroll
    for (int g4 = 0; g4 < 4; ++g4) {
      float4 o;
      o.x = oac[dt][4 * g4 + 0] * inv;
      o.y = oac[dt][4 * g4 + 1] * inv;
      o.z = oac[dt][4 * g4 + 2] * inv;
      o.w = oac[dt][4 * g4 + 3] * inv;
      const int d = dt * 32 + g4 * 8 + h * 4;
      *(float4*)&out[((size_t)(b * 2048 + qrow)) * 2048 + hd * 128 + d] = o;
    }
  }
}

extern "C" void kernel_launch(void* const* d_in, const int* in_sizes, int n_in,
                              void* d_out, int out_size, void* d_ws, size_t ws_size,
                              hipStream_t stream) {
  const float* x  = (const float*)d_in[0];
  const float* Wq = (const float*)d_in[1];
  const float* bq = (const float*)d_in[2];
  const float* Wk = (const float*)d_in[3];
  const float* bk = (const float*)d_in[4];
  const float* Wv = (const float*)d_in[5];
  const float* bv = (const float*)d_in[6];
  float* out = (float*)d_out;
  if (ws_size < 92274688u) return;

  u16* xb  = (u16*)d_ws;             // [4096][2048] bf16
  u16* Wb  = xb + 8388608;           // [3][2048][2048] bf16
  u16* qkv = Wb + 12582912;          // Q | K | V^T bf16

  cvt_kernel<<<4096, 256, 0, stream>>>(x, xb, 1048576);
  cvtw_kernel<<<dim3(2048, 3), 256, 0, stream>>>(Wq, Wk, Wv, Wb);
  qkv_gemm<<<dim3(8, 16, 3), 512, 131072, stream>>>(xb, Wb, bq, bk, bv, qkv);
  attn_kernel<<<dim3(16, 32), 256, 0, stream>>>(qkv, qkv + 8388608, qkv + 16777216, out);
}